// Round 1
// baseline (115.837 us; speedup 1.0000x reference)
//
#include <hip/hip_runtime.h>

// Problem constants (from reference): B=16 batches, A=5 agents, C=512 ch, H=W=16.
#define NB 16
#define NA 5
#define NC 512
#define HW 256   // 16*16

typedef float f4 __attribute__((ext_vector_type(4)));

// Block = (batch b, 4-channel group g). 256 threads = one thread per pixel.
// LDS: all 5 agents' 4-channel slabs, channel-interleaved (float4 per pixel)
// so a single ds_read_b128 fetches one bilinear tap for 4 channels.
// Two-stage warp exactly matches reference: rotation grid_sample (per-pixel
// affine sample of lds_src[j]) -> lds_fr; translation grid_sample (constant
// fractional shift per pair) of lds_fr -> accumulate into agent i.
__global__ __launch_bounds__(256) void fafmimo_fuse_kernel(
    const float* __restrict__ feat,   // [A*B][C][256], feat[a*B+b] = local[b][a]
    const float* __restrict__ trans,  // [B][A][A][4][4]
    const int*   __restrict__ numa,   // [B][A], use [:,0]
    float*       __restrict__ out)    // [A*B][C][256]
{
    __shared__ f4 lds_src[NA][HW];  // 20 KiB
    __shared__ f4 lds_fr[HW];       //  4 KiB

    const int bx = blockIdx.x;
    const int b  = bx & (NB - 1);    // batch fastest: mixes imbalanced batches across CUs
    const int g  = bx >> 4;          // channel group 0..127
    const int c0 = g << 2;
    const int p  = threadIdx.x;      // pixel 0..255
    const int x  = p & 15, y = p >> 4;
    const float fx = (float)x - 7.5f;
    const float fy = (float)y - 7.5f;
    const int n = numa[b * NA];      // num_agent_tensor[b, 0]

    // Stage all agents' 4-channel slab into LDS (each HBM byte read exactly once).
    f4 local_v[NA];
#pragma unroll
    for (int a = 0; a < NA; ++a) {
        const float* src = feat + ((a * NB + b) * NC + c0) * HW + p;
        f4 v;
        v.x = src[0];
        v.y = src[HW];
        v.z = src[2 * HW];
        v.w = src[3 * HW];
        lds_src[a][p] = v;
        local_v[a] = v;              // residual term, kept in registers
    }
    __syncthreads();

    for (int i = 0; i < NA; ++i) {
        f4 acc = local_v[i];         // fused = local + masked pair sum

        if (i < n) {
            for (int j = 0; j < n; ++j) {
                if (j == i) continue;   // uniform control flow: n, i, j block-uniform

                // trans[b][i][j] rows 0,1 as two float4 scalar loads
                const f4* twv = (const f4*)(trans + (((b * NA) + i) * NA + j) * 16);
                const f4 row0 = twv[0];   // r00 r01 _ tx
                const f4 row1 = twv[1];   // r10 r11 _ ty

                // ---- stage 1: rotation grid_sample at this thread's pixel ----
                // ix_r = r00*(x-7.5) + r01*(y-7.5) + 7.5 (align_corners=False algebra)
                const float ixr = row0.x * fx + row0.y * fy + 7.5f;
                const float iyr = row1.x * fx + row1.y * fy + 7.5f;
                const float fx0 = floorf(ixr), fy0 = floorf(iyr);
                const float wx1 = ixr - fx0, wx0 = 1.0f - wx1;
                const float wy1 = iyr - fy0, wy0 = 1.0f - wy1;
                const int ix0 = (int)fx0, iy0 = (int)fy0;
                const int ix1 = ix0 + 1,  iy1 = iy0 + 1;
                // zero-padding: out-of-bounds tap => weight 0, address clamped (safe read)
                const float mx0 = (ix0 >= 0 && ix0 < 16) ? wx0 : 0.0f;
                const float mx1 = (ix1 >= 0 && ix1 < 16) ? wx1 : 0.0f;
                const float my0 = (iy0 >= 0 && iy0 < 16) ? wy0 : 0.0f;
                const float my1 = (iy1 >= 0 && iy1 < 16) ? wy1 : 0.0f;
                const int cx0 = min(max(ix0, 0), 15), cx1 = min(max(ix1, 0), 15);
                const int cy0 = min(max(iy0, 0), 15), cy1 = min(max(iy1, 0), 15);
                const f4 v00 = lds_src[j][cy0 * 16 + cx0];
                const f4 v01 = lds_src[j][cy0 * 16 + cx1];
                const f4 v10 = lds_src[j][cy1 * 16 + cx0];
                const f4 v11 = lds_src[j][cy1 * 16 + cx1];
                const f4 fr = (v00 * mx0 + v01 * mx1) * my0
                            + (v10 * mx0 + v11 * mx1) * my1;

                __syncthreads();          // prev pair's stage-2 reads done
                lds_fr[p] = fr;
                __syncthreads();          // fr visible to neighbors

                // ---- stage 2: translation grid_sample of fr ----
                // ix_t = x + tx/4, iy_t = y - ty/4 (constant shift per pair)
                const float dx = 0.25f * row0.w;
                const float dy = -0.25f * row1.w;
                const float fdx = floorf(dx), fdy = floorf(dy);
                const float tx1 = dx - fdx, tx0 = 1.0f - tx1;
                const float ty1 = dy - fdy, ty0 = 1.0f - ty1;
                const int ox = x + (int)fdx;
                const int oy = y + (int)fdy;
                const float wxa = (ox     >= 0 && ox     < 16) ? tx0 : 0.0f;
                const float wxb = (ox + 1 >= 0 && ox + 1 < 16) ? tx1 : 0.0f;
                const float wya = (oy     >= 0 && oy     < 16) ? ty0 : 0.0f;
                const float wyb = (oy + 1 >= 0 && oy + 1 < 16) ? ty1 : 0.0f;
                const int cxa = min(max(ox, 0), 15),     cxb = min(max(ox + 1, 0), 15);
                const int cya = min(max(oy, 0), 15),     cyb = min(max(oy + 1, 0), 15);
                const f4 t00 = lds_fr[cya * 16 + cxa];
                const f4 t01 = lds_fr[cya * 16 + cxb];
                const f4 t10 = lds_fr[cyb * 16 + cxa];
                const f4 t11 = lds_fr[cyb * 16 + cxb];
                acc += (t00 * wxa + t01 * wxb) * wya
                     + (t10 * wxa + t11 * wxb) * wyb;
            }
        }

        // store fused[b][i] -> out[i*B+b]
        float* dst = out + ((i * NB + b) * NC + c0) * HW + p;
        dst[0]      = acc.x;
        dst[HW]     = acc.y;
        dst[2 * HW] = acc.z;
        dst[3 * HW] = acc.w;
    }
}

extern "C" void kernel_launch(void* const* d_in, const int* in_sizes, int n_in,
                              void* d_out, int out_size, void* d_ws, size_t ws_size,
                              hipStream_t stream) {
    const float* feat  = (const float*)d_in[0];
    const float* trans = (const float*)d_in[1];
    const int*   numa  = (const int*)d_in[2];
    float* out = (float*)d_out;

    // grid: 16 batches x 128 channel-groups; batch varies fastest
    fafmimo_fuse_kernel<<<dim3(NB * (NC / 4)), dim3(256), 0, stream>>>(
        feat, trans, numa, out);
}